// Round 4
// baseline (506.563 us; speedup 1.0000x reference)
//
#include <hip/hip_runtime.h>

#define B_ 8
#define N_ 4096
#define D_ 512
#define K_ 1025

// LDS index space I in [0, 5120): [0,512)=left zero pad, [512,4608)=q column,
// [4608,5120)=right zero pad. Physical layout inserts 4 pad floats per 32 so
// that 16-element windows starting at multiples of 16 stay contiguous AND
// 16B-aligned, while breaking the stride-16 bank pattern.
#define LDSN 5120
#define PHYS(I) ((I) + ((((I) >> 5)) << 2))

// Load 16 consecutive logical floats (I0 must be a multiple of 16).
// NOTE: dest parameter must NOT be named 'w'/'x'/'y'/'z' — the preprocessor
// substitutes macro params even after '.', clobbering float4 member access.
#define LOAD16(DST_, I0expr)                                               \
  do {                                                                     \
    int I0_ = (I0expr);                                                    \
    int p_ = PHYS(I0_);                                                    \
    const float4* s_ = reinterpret_cast<const float4*>(qs + p_);           \
    float4 v0_ = s_[0], v1_ = s_[1], v2_ = s_[2], v3_ = s_[3];             \
    DST_[0] = v0_.x;  DST_[1] = v0_.y;  DST_[2] = v0_.z;  DST_[3] = v0_.w; \
    DST_[4] = v1_.x;  DST_[5] = v1_.y;  DST_[6] = v1_.z;  DST_[7] = v1_.w; \
    DST_[8] = v2_.x;  DST_[9] = v2_.y;  DST_[10] = v2_.z; DST_[11] = v2_.w;\
    DST_[12] = v3_.x; DST_[13] = v3_.y; DST_[14] = v3_.z; DST_[15] = v3_.w;\
  } while (0)

// 16 filter taps against ping-pong window buffers; all indices compile-time.
#define STEP16(fp, WA_, WB_)                                               \
  do {                                                                     \
    _Pragma("unroll") for (int u_ = 0; u_ < 16; ++u_) {                    \
      float fv_ = (fp)[u_];                                                \
      _Pragma("unroll") for (int r_ = 0; r_ < 16; ++r_) {                  \
        int j_ = u_ + r_;                                                  \
        float x_ = (j_ < 16) ? WA_[j_] : WB_[j_ - 16];                     \
        acc[r_] = fmaf(fv_, x_, acc[r_]);                                  \
      }                                                                    \
    }                                                                      \
  } while (0)

__global__ __launch_bounds__(256) void kmean_kernel(
    const float* __restrict__ k, float* __restrict__ kmean) {
  int bid = blockIdx.x;
  int nchunk = bid & 15;        // 16 chunks of 256 rows
  int dgrp = (bid >> 4) & 1;    // D/256 = 2
  int b = bid >> 5;             // 8 batches
  int d = (dgrp << 8) + threadIdx.x;
  const float* __restrict__ base =
      k + ((size_t)b * N_ + (size_t)nchunk * 256) * D_ + d;
  float s = 0.f;
#pragma unroll 8
  for (int i = 0; i < 256; ++i) s += base[(size_t)i * D_];
  atomicAdd(&kmean[b * D_ + d], s);
}

__global__ __launch_bounds__(256) void conv_kernel(
    const float* __restrict__ q, const float* __restrict__ filt,
    const float* __restrict__ kmean, float* __restrict__ out) {
  __shared__ float qs[PHYS(LDSN)];  // 5760 floats = 23 KB

  const int i = blockIdx.x;
  const int b = i & 7;   // batch pinned per-XCD (round-robin dispatch)
  const int d = i >> 3;  // consecutive slots = consecutive d -> L2-local writes
  const int tid = threadIdx.x;

  // ---- stage the zero-padded q column into LDS ----
  const float* __restrict__ qcol = q + (size_t)b * N_ * D_ + d;
#pragma unroll
  for (int I = tid; I < 512; I += 256) {
    qs[PHYS(I)] = 0.f;
    int J = I + 4608;
    qs[PHYS(J)] = 0.f;
  }
#pragma unroll 4
  for (int n = tid; n < N_; n += 256) {
    int I = n + 512;
    qs[PHYS(I)] = qcol[(size_t)n * D_];
  }
  __syncthreads();

  // ---- depthwise correlation: 16 outputs/thread, sliding register window ----
  const float* __restrict__ f = filt + (size_t)d * K_;  // wave-uniform -> s_load
  float acc[16], wA[16], wB[16];
#pragma unroll
  for (int r = 0; r < 16; ++r) acc[r] = 0.f;
  const int obase = tid << 4;  // output rows [obase, obase+16)

  LOAD16(wA, obase);  // window for t = 0
#pragma unroll 1
  for (int t = 0; t < 1024; t += 32) {
    LOAD16(wB, obase + t + 16);
    STEP16(f + t, wA, wB);
    LOAD16(wA, obase + t + 32);
    STEP16(f + t + 16, wB, wA);
  }
  {  // tail tap t = 1024 (K = 1025)
    float fv = f[1024];
#pragma unroll
    for (int r = 0; r < 16; ++r) acc[r] = fmaf(fv, wA[r], acc[r]);
  }

  const float scale = kmean[b * D_ + d] * (1.0f / 4096.0f);
  float* __restrict__ ocol = out + (size_t)b * N_ * D_ + d;
#pragma unroll
  for (int r = 0; r < 16; ++r) ocol[(size_t)(obase + r) * D_] = acc[r] * scale;
}

extern "C" void kernel_launch(void* const* d_in, const int* in_sizes, int n_in,
                              void* d_out, int out_size, void* d_ws,
                              size_t ws_size, hipStream_t stream) {
  const float* q = (const float*)d_in[0];
  const float* k = (const float*)d_in[1];
  const float* filt = (const float*)d_in[2];
  float* out = (float*)d_out;
  float* kmean = (float*)d_ws;  // B_*D_ floats = 16 KB

  (void)hipMemsetAsync(kmean, 0, B_ * D_ * sizeof(float), stream);
  kmean_kernel<<<256, 256, 0, stream>>>(k, kmean);
  conv_kernel<<<B_ * D_, 256, 0, stream>>>(q, filt, kmean, out);
}

// Round 5
// 456.908 us; speedup vs baseline: 1.1087x; 1.1087x over previous
//
#include <hip/hip_runtime.h>

typedef _Float16 half8 __attribute__((ext_vector_type(8)));
typedef float f32x4 __attribute__((ext_vector_type(4)));

#define B_ 8
#define N_ 4096
#define D_ 512
#define K_ 1025

#define HALF_N 2048   // outputs per block (half a column)
#define QWIN 3104     // staged q-window elements (local w: q[hbase + w - 512])
#define CSTR 3144     // copy stride, mult of 8, (CSTR/2) % 32 == 4 (bank spread)
#define FSZ 1528      // padded filter: t in [-240, 1287], fs[e] = f[e-240]

__global__ __launch_bounds__(256) void kmean_kernel(
    const float* __restrict__ k, float* __restrict__ kmean) {
  int bid = blockIdx.x;
  int nchunk = bid & 63;        // 64 chunks of 64 rows
  int dgrp = (bid >> 6) & 1;    // D/256 = 2
  int b = bid >> 7;             // 8 batches
  int d = (dgrp << 8) + threadIdx.x;
  const float* __restrict__ base =
      k + ((size_t)b * N_ + (size_t)nchunk * 64) * D_ + d;
  float s = 0.f;
#pragma unroll 8
  for (int i = 0; i < 64; ++i) s += base[(size_t)i * D_];
  atomicAdd(&kmean[b * D_ + d], s);
}

// One block = one (b, d, half-column). 128 threads = 2 waves; each wave owns
// 4 tiles of 256 outputs. C[i][j] = out[n0 + 16i + j] = sum_k A[i][k]*B[k][j],
// A[i][k] = f[k-16i] (flat padded filter, aligned reads), B[k][j] = q-window
// (Hankel; 8 shift-staged LDS copies make every b128 read 16B-aligned).
__global__ __launch_bounds__(128) void conv_mfma(
    const float* __restrict__ q, const float* __restrict__ filt,
    const float* __restrict__ kmean, float* __restrict__ out) {
  __shared__ alignas(16) _Float16 qcop[8 * CSTR];  // 50304 B
  __shared__ alignas(16) _Float16 fsh[FSZ];        //  3056 B

  const int i = blockIdx.x;
  const int b = i & 7;           // same XCD-friendly mapping as proven r4 kernel
  const int d = (i >> 3) & 511;
  const int h = i >> 12;         // half-column index
  const int hbase = h * HALF_N;
  const int tid = threadIdx.x;

  // ---- stage padded filter (fp32 -> fp16) ----
  for (int e = tid; e < FSZ; e += 128) {
    int t = e - 240;
    float v = (t >= 0 && t < K_) ? filt[(size_t)d * K_ + t] : 0.f;
    fsh[e] = (_Float16)v;
  }
  // ---- stage q window into 8 shifted copies: qcop[c][e] = qwin[e + c] ----
  for (int w = tid; w < QWIN; w += 128) {
    int gi = hbase + w - 512;
    float v = (gi >= 0 && gi < N_)
                  ? q[((size_t)b * N_ + gi) * D_ + d]
                  : 0.f;
    _Float16 hv = (_Float16)v;
#pragma unroll
    for (int c = 0; c < 8; ++c) {
      if (w >= c) qcop[c * CSTR + (w - c)] = hv;
    }
  }
  __syncthreads();

  const int lane = tid & 63;
  const int wv = tid >> 6;       // wave id: owns tiles wv*1024 + {0,256,512,768}
  const int j = lane & 15;       // B col / C col
  const int kb = lane >> 4;      // k-block (8 elems each)
  const int ii = lane & 15;      // A row / C row-group

  // per-lane element bases (all ≡ 0 mod 8 -> 16B-aligned b128)
  const int abase = 240 + kb * 8 - 16 * ii;                       // + 32*s
  const int bbase = (j & 7) * CSTR + kb * 8 + 8 * (j >> 3);       // + n0 + 32*s

  f32x4 acc0 = {0.f, 0.f, 0.f, 0.f};
  f32x4 acc1 = {0.f, 0.f, 0.f, 0.f};
  f32x4 acc2 = {0.f, 0.f, 0.f, 0.f};
  f32x4 acc3 = {0.f, 0.f, 0.f, 0.f};
  const int nb = wv * 1024;

#pragma unroll 2
  for (int s = 0; s < 40; ++s) {
    const int so = 32 * s;
    half8 af = *(const half8*)(fsh + abase + so);
    half8 b0 = *(const half8*)(qcop + bbase + nb + 0 + so);
    half8 b1 = *(const half8*)(qcop + bbase + nb + 256 + so);
    half8 b2 = *(const half8*)(qcop + bbase + nb + 512 + so);
    half8 b3 = *(const half8*)(qcop + bbase + nb + 768 + so);
    acc0 = __builtin_amdgcn_mfma_f32_16x16x32_f16(af, b0, acc0, 0, 0, 0);
    acc1 = __builtin_amdgcn_mfma_f32_16x16x32_f16(af, b1, acc1, 0, 0, 0);
    acc2 = __builtin_amdgcn_mfma_f32_16x16x32_f16(af, b2, acc2, 0, 0, 0);
    acc3 = __builtin_amdgcn_mfma_f32_16x16x32_f16(af, b3, acc3, 0, 0, 0);
  }

  // ---- epilogue: C col = lane&15 = j, row = kb*4 + r  (m89 layout) ----
  const float scale = kmean[b * D_ + d] * (1.0f / 4096.0f);
  float* __restrict__ ob = out + (size_t)b * N_ * D_ + d;
#pragma unroll
  for (int t = 0; t < 4; ++t) {
    f32x4 a = (t == 0) ? acc0 : (t == 1) ? acc1 : (t == 2) ? acc2 : acc3;
#pragma unroll
    for (int r = 0; r < 4; ++r) {
      int n = hbase + nb + t * 256 + 64 * kb + 16 * r + j;
      ob[(size_t)n * D_] = (float)a[r] * scale;
    }
  }
}

extern "C" void kernel_launch(void* const* d_in, const int* in_sizes, int n_in,
                              void* d_out, int out_size, void* d_ws,
                              size_t ws_size, hipStream_t stream) {
  const float* q = (const float*)d_in[0];
  const float* k = (const float*)d_in[1];
  const float* filt = (const float*)d_in[2];
  float* out = (float*)d_out;
  float* kmean = (float*)d_ws;  // B_*D_ floats = 16 KB

  (void)hipMemsetAsync(kmean, 0, B_ * D_ * sizeof(float), stream);
  kmean_kernel<<<1024, 256, 0, stream>>>(k, kmean);
  conv_mfma<<<B_ * D_ * 2, 128, 0, stream>>>(q, filt, kmean, out);
}

// Round 7
// 342.072 us; speedup vs baseline: 1.4809x; 1.3357x over previous
//
#include <hip/hip_runtime.h>

typedef _Float16 half8 __attribute__((ext_vector_type(8)));
typedef float f32x4 __attribute__((ext_vector_type(4)));

#define B_ 8
#define N_ 4096
#define D_ 512
#define K_ 1025

#define NSTEP 33      // k-steps of 32: Kpad = 1056 >= 1025 + 15
#define FSTR 1080     // filter-copy stride (elems): mult of 8, FSTR/8 odd (bank spread)
#define QWIN 5152     // single q-window: n in [0,4096) + taps, 16B-padded
#define KM_OFF 262144 // ws float offset of kmean (after 1024*256 partials)

// ---- kmean stage 1: 1024 blocks write partial sums (no atomics) ----
__global__ __launch_bounds__(256) void kmean1(
    const float* __restrict__ k, float* __restrict__ part) {
  int bid = blockIdx.x;
  int dgrp = bid & 1;
  int chunk = (bid >> 1) & 63;   // 64 chunks of 64 rows
  int b = bid >> 7;
  int tid = threadIdx.x;
  const float* __restrict__ base =
      k + ((size_t)b * N_ + (size_t)chunk * 64) * D_ + dgrp * 256 + tid;
  float s = 0.f;
#pragma unroll 8
  for (int i = 0; i < 64; ++i) s += base[(size_t)i * D_];
  part[((size_t)(b * 2 + dgrp) * 64 + chunk) * 256 + tid] = s;
}

// ---- kmean stage 2: 16 blocks reduce 64 partials each ----
__global__ __launch_bounds__(256) void kmean2(float* __restrict__ ws) {
  int bid = blockIdx.x;
  int b = bid >> 1, dgrp = bid & 1;
  int tid = threadIdx.x;
  const float* __restrict__ p = ws + ((size_t)(b * 2 + dgrp) * 64) * 256 + tid;
  float s = 0.f;
#pragma unroll 8
  for (int c = 0; c < 64; ++c) s += p[c * 256];
  ws[KM_OFF + b * D_ + dgrp * 256 + tid] = s;
}

// One block = one (b,d) FULL column (4096 outputs). 256 thr = 4 waves, each
// wave owns 4 tiles of 256. Tile: C[i][j] = out[n0 + i + 16j]
//   A[i][k] = f[k - i]  -> 8 shifted filter copies in LDS (i&7 picks copy)
//   B[k][j] = qpad[n0 + 16j + k] -> 16j = 0 mod 8: single window, aligned b128
__global__ __launch_bounds__(256) void conv_mfma(
    const float* __restrict__ q, const float* __restrict__ filt,
    const float* __restrict__ kmean, float* __restrict__ out) {
  __shared__ alignas(16) _Float16 fsh[8 * FSTR];  // 17280 B
  __shared__ alignas(16) _Float16 qsw[QWIN];      // 10304 B

  const int i = blockIdx.x;
  const int b = i & 7;           // XCD-friendly mapping (proven r4/r5)
  const int d = i >> 3;          // 0..511
  const int tid = threadIdx.x;

  // ---- stage filter copies: fsh[c][e] = f[e - 8 - c] (zero-padded) ----
  // diagonal write: one global load covers all 8 copies
  const float* __restrict__ fcol = filt + (size_t)d * K_;
  for (int m = tid; m < 1072; m += 256) {
    int t = m - 8;
    _Float16 hv = (_Float16)((t >= 0 && t < K_) ? fcol[t] : 0.f);
#pragma unroll
    for (int c = 0; c < 8; ++c) fsh[c * FSTR + m + c] = hv;
  }
  if (tid < 64) {  // cells e < c (m<0 diagonal) must be zero
    int c = tid >> 3, e = tid & 7;
    if (e < c) fsh[c * FSTR + e] = (_Float16)0.f;
  }

  // ---- stage q window once: qsw[w] = qpad[w] = q[w-512] (zero-padded) ----
  const float* __restrict__ qcol = q + (size_t)b * N_ * D_ + d;
  for (int w = tid; w < QWIN; w += 256) {
    int gi = w - 512;
    float v = (gi >= 0 && gi < N_) ? qcol[(size_t)gi * D_] : 0.f;
    qsw[w] = (_Float16)v;
  }
  __syncthreads();

  // ---- MFMA phase ----
  const int lane = tid & 63;
  const int wv = tid >> 6;        // wave -> n-range [wv*1024, wv*1024+1024)
  const int l4 = lane & 15;       // = A row i = B col j
  const int kb = lane >> 4;       // k-block of 8
  const int c = l4 & 7, hi = l4 >> 3;

  const _Float16* __restrict__ ap = fsh + c * FSTR + 8 + 8 * kb - 8 * hi;
  const _Float16* __restrict__ bp = qsw + wv * 1024 + 16 * l4 + 8 * kb;

  f32x4 acc0 = {0.f, 0.f, 0.f, 0.f};
  f32x4 acc1 = {0.f, 0.f, 0.f, 0.f};
  f32x4 acc2 = {0.f, 0.f, 0.f, 0.f};
  f32x4 acc3 = {0.f, 0.f, 0.f, 0.f};

#pragma unroll
  for (int s = 0; s < NSTEP; ++s) {
    half8 af = *(const half8*)(ap + 32 * s);
    half8 b0 = *(const half8*)(bp + 32 * s);
    half8 b1 = *(const half8*)(bp + 256 + 32 * s);
    half8 b2 = *(const half8*)(bp + 512 + 32 * s);
    half8 b3 = *(const half8*)(bp + 768 + 32 * s);
    acc0 = __builtin_amdgcn_mfma_f32_16x16x32_f16(af, b0, acc0, 0, 0, 0);
    acc1 = __builtin_amdgcn_mfma_f32_16x16x32_f16(af, b1, acc1, 0, 0, 0);
    acc2 = __builtin_amdgcn_mfma_f32_16x16x32_f16(af, b2, acc2, 0, 0, 0);
    acc3 = __builtin_amdgcn_mfma_f32_16x16x32_f16(af, b3, acc3, 0, 0, 0);
  }

  // ---- epilogue: C col = l4 (=j), row = 4*kb + r (=i); n = n0 + i + 16j ----
  const float scale = kmean[b * D_ + d] * (1.0f / 4096.0f);
  float* __restrict__ ob = out + (size_t)b * N_ * D_ + d;
#pragma unroll
  for (int t = 0; t < 4; ++t) {
    f32x4 a = (t == 0) ? acc0 : (t == 1) ? acc1 : (t == 2) ? acc2 : acc3;
    int nbase = wv * 1024 + t * 256 + 16 * l4 + 4 * kb;
#pragma unroll
    for (int r = 0; r < 4; ++r) {
      ob[(size_t)(nbase + r) * D_] = (float)a[r] * scale;
    }
  }
}

extern "C" void kernel_launch(void* const* d_in, const int* in_sizes, int n_in,
                              void* d_out, int out_size, void* d_ws,
                              size_t ws_size, hipStream_t stream) {
  const float* q = (const float*)d_in[0];
  const float* k = (const float*)d_in[1];
  const float* filt = (const float*)d_in[2];
  float* out = (float*)d_out;
  float* ws = (float*)d_ws;  // partials (1 MB) + kmean (16 KB)

  kmean1<<<1024, 256, 0, stream>>>(k, ws);
  kmean2<<<16, 256, 0, stream>>>(ws);
  conv_mfma<<<B_ * D_, 256, 0, stream>>>(q, filt, ws + KM_OFF, out);
}